// Round 1
// baseline (19948.816 us; speedup 1.0000x reference)
//
#include <hip/hip_runtime.h>
#include <cmath>

// Problem constants (from reference): B=64, NH=256, T=4096, KS=5, STRIDE=2,
// DEPTH_VARIANT=1 -> conv1 in-channels = 257. 12 depths (4096 -> 1).

// ---------------- setup: finish_depth + stable argsort rank ----------------
__global__ void setup_kernel(const int* __restrict__ N0, int* __restrict__ rankfd) {
    __shared__ int fd_s[64];
    int b = threadIdx.x;  // 64 threads
    int n = N0[b];
    int d = 0;
    while ((1 << (d + 1)) < n) ++d;   // smallest d with n <= 2^(d+1)
    fd_s[b] = d;
    __syncthreads();
    int myfd = fd_s[b];
    int r = 0;
    for (int i = 0; i < 64; ++i) {
        int f = fd_s[i];
        r += (f < myfd || (f == myfd && i < b)) ? 1 : 0;
    }
    rankfd[b] = r;        // captured[b] goes to out row r
    rankfd[64 + b] = myfd;
}

// --------- weight transpose: w[oc][c][k] -> wT[(c*5+k)][oc] (vec loads) ----
__global__ void transpose_kernel(const float* __restrict__ w1, const float* __restrict__ w2,
                                 float* __restrict__ wT1, float* __restrict__ wT2) {
    int i = blockIdx.x * 256 + threadIdx.x;
    if (i < 512 * 1285) {
        int oc = i / 1285, rem = i - oc * 1285;   // rem = c*5+k
        wT1[rem * 512 + oc] = w1[i];
    }
    if (i < 256 * 1280) {
        int oc = i / 1280, rem = i - oc * 1280;
        wT2[rem * 256 + oc] = w2[i];
    }
}

// ---------------- conv1: lr = conv(hh_masked, w1, stride 2) ----------------
// Block: 256 thr = 4 waves; wave -> 8 ocs; lane -> 8 output times.
// Writes l (+bias) into lbuf, r = mask(relu(+bias)) into rbuf.
__global__ __launch_bounds__(256, 2)
void conv1_kernel(const float* __restrict__ h, const float* __restrict__ wT1,
                  const float* __restrict__ b1, const int* __restrict__ N0,
                  float* __restrict__ lbuf, float* __restrict__ rbuf,
                  int T_in, int T_out, int depth, float logd) {
    const int wave = threadIdx.x >> 6;
    const int lane = threadIdx.x & 63;
    const int b = blockIdx.z;
    const int oc0 = blockIdx.y * 32 + wave * 8;     // 16 y-blocks cover 512 ocs
    const int t0 = blockIdx.x * 512 + lane * 8;
    if (t0 >= T_out) return;
    const int n0 = N0[b];
    const int Nb = (n0 + (1 << depth) - 1) >> depth;   // current mask length
    const int Nn = (Nb + 1) >> 1;                      // mask length after stride-2
    const int base = 2 * t0 - 4;                       // aligned load base (mult of 4)

    float acc[8][8];
#pragma unroll
    for (int j = 0; j < 8; ++j)
#pragma unroll
        for (int i = 0; i < 8; ++i) acc[j][i] = 0.f;

    if (base + 2 < Nb) {   // else: whole window masked -> acc stays 0
        const bool fast = (base >= 0) && (base + 24 <= Nb);
        for (int c = 0; c < 257; ++c) {
            float v[24];   // input positions base .. base+23 (used: idx 2..20)
            if (c < 256) {
                const float* hp = h + ((size_t)(b * 256 + c)) * T_in;
                if (fast) {
#pragma unroll
                    for (int q = 0; q < 6; ++q) {
                        float4 f = *(const float4*)(hp + base + 4 * q);
                        v[4 * q + 0] = f.x; v[4 * q + 1] = f.y;
                        v[4 * q + 2] = f.z; v[4 * q + 3] = f.w;
                    }
                } else {
#pragma unroll
                    for (int idx = 0; idx < 24; ++idx) {
                        int p = base + idx;
                        v[idx] = (p >= 0 && p < Nb) ? hp[p] : 0.f;
                    }
                }
            } else {  // depth channel: constant log1p(depth), masked by Nb
#pragma unroll
                for (int idx = 0; idx < 24; ++idx) {
                    int p = base + idx;
                    v[idx] = (p >= 0 && p < Nb) ? logd : 0.f;
                }
            }
#pragma unroll
            for (int k = 0; k < 5; ++k) {
                const float* wp = wT1 + (size_t)(c * 5 + k) * 512 + oc0;
                float4 wa = *(const float4*)wp;
                float4 wb = *(const float4*)(wp + 4);
                float w8[8] = {wa.x, wa.y, wa.z, wa.w, wb.x, wb.y, wb.z, wb.w};
#pragma unroll
                for (int j = 0; j < 8; ++j)
#pragma unroll
                    for (int i = 0; i < 8; ++i)
                        acc[j][i] += w8[j] * v[2 + 2 * i + k];   // pos = 2(t0+i)+k-2
            }
        }
    }

    const bool isl = (oc0 < 256);
#pragma unroll
    for (int j = 0; j < 8; ++j) {
        const int oc = oc0 + j;
        const float bias = b1[oc];
        if (isl) {
            float* op = lbuf + ((size_t)(b * 256 + oc)) * T_out + t0;
#pragma unroll
            for (int i = 0; i < 8; ++i)
                if (t0 + i < T_out) op[i] = acc[j][i] + bias;
        } else {
            float* op = rbuf + ((size_t)(b * 256 + (oc - 256))) * T_out + t0;
#pragma unroll
            for (int i = 0; i < 8; ++i)
                if (t0 + i < T_out) {
                    float val = acc[j][i] + bias;
                    val = val > 0.f ? val : 0.f;      // relu
                    if (t0 + i >= Nn) val = 0.f;      // seq_mask with new N
                    op[i] = val;
                }
        }
    }
}

// ------------- conv2: h = relu(l + conv(r, w2, stride 1) + b2) -------------
// Reads l from hbuf (written by conv1), overwrites hbuf with new h.
// Captures h[:, :, 0] into out[rank[b]] when depth == finish_depth[b].
__global__ __launch_bounds__(256, 2)
void conv2_kernel(const float* __restrict__ rbuf, const float* __restrict__ wT2,
                  const float* __restrict__ b2, const int* __restrict__ N0,
                  const int* __restrict__ rankfd, float* __restrict__ hbuf,
                  float* __restrict__ out, int T, int depth) {
    const int wave = threadIdx.x >> 6;
    const int lane = threadIdx.x & 63;
    const int b = blockIdx.z;
    const int oc0 = blockIdx.y * 32 + wave * 8;     // 8 y-blocks cover 256 ocs
    const int t0 = blockIdx.x * 512 + lane * 8;
    if (t0 >= T) return;
    const int n0 = N0[b];
    const int Nn = (n0 + (1 << (depth + 1)) - 1) >> (depth + 1);
    const int base = t0 - 4;   // mult of 4

    float acc[8][8];
#pragma unroll
    for (int j = 0; j < 8; ++j)
#pragma unroll
        for (int i = 0; i < 8; ++i) acc[j][i] = 0.f;

    if (base + 2 < Nn) {   // r is pre-masked to 0 beyond Nn
        const bool fast = (base >= 0) && (base + 16 <= T);
        for (int c = 0; c < 256; ++c) {
            const float* rp = rbuf + ((size_t)(b * 256 + c)) * T;
            float v[16];   // positions base .. base+15 (used: idx 2..14)
            if (fast) {
#pragma unroll
                for (int q = 0; q < 4; ++q) {
                    float4 f = *(const float4*)(rp + base + 4 * q);
                    v[4 * q + 0] = f.x; v[4 * q + 1] = f.y;
                    v[4 * q + 2] = f.z; v[4 * q + 3] = f.w;
                }
            } else {
#pragma unroll
                for (int idx = 0; idx < 16; ++idx) {
                    int p = base + idx;
                    v[idx] = (p >= 0 && p < T) ? rp[p] : 0.f;
                }
            }
#pragma unroll
            for (int k = 0; k < 5; ++k) {
                const float* wp = wT2 + (size_t)(c * 5 + k) * 256 + oc0;
                float4 wa = *(const float4*)wp;
                float4 wb = *(const float4*)(wp + 4);
                float w8[8] = {wa.x, wa.y, wa.z, wa.w, wb.x, wb.y, wb.z, wb.w};
#pragma unroll
                for (int j = 0; j < 8; ++j)
#pragma unroll
                    for (int i = 0; i < 8; ++i)
                        acc[j][i] += w8[j] * v[2 + i + k];   // pos = t0+i+k-2
            }
        }
    }

    const int rk = rankfd[b];
    const int fd = rankfd[64 + b];
    const bool cap = (fd == depth) && (t0 == 0);
#pragma unroll
    for (int j = 0; j < 8; ++j) {
        const int oc = oc0 + j;
        const float bias = b2[oc];
        float* hp = hbuf + ((size_t)(b * 256 + oc)) * T + t0;
#pragma unroll
        for (int i = 0; i < 8; ++i)
            if (t0 + i < T) {
                float val = hp[i] + acc[j][i] + bias;   // hp[i] holds l (+b1)
                val = val > 0.f ? val : 0.f;
                hp[i] = val;
                if (cap && i == 0) out[rk * 256 + oc] = val;
            }
    }
}

// --------------------------------- launch ----------------------------------
extern "C" void kernel_launch(void* const* d_in, const int* in_sizes, int n_in,
                              void* d_out, int out_size, void* d_ws, size_t ws_size,
                              hipStream_t stream) {
    const float* h  = (const float*)d_in[0];
    const int*   N0 = (const int*)d_in[1];
    const float* w1 = (const float*)d_in[2];
    const float* b1 = (const float*)d_in[3];
    const float* w2 = (const float*)d_in[4];
    const float* b2 = (const float*)d_in[5];
    float* out = (float*)d_out;

    // Workspace layout (floats unless noted):
    //   [0,1024)B: rankfd int[128]
    //   wT1: 1285*512  | wT2: 1280*256
    //   H0: 64*256*2048 | H1: 64*256*1024 | R: 64*256*2048   (~340 MB total)
    char* ws = (char*)d_ws;
    int*   rankfd = (int*)ws;
    float* wT1 = (float*)(ws + 1024);
    float* wT2 = wT1 + 512 * 1285;
    float* H0  = wT2 + 256 * 1280;
    float* H1  = H0 + (size_t)64 * 256 * 2048;
    float* R   = H1 + (size_t)64 * 256 * 1024;

    setup_kernel<<<1, 64, 0, stream>>>(N0, rankfd);
    transpose_kernel<<<(512 * 1285 + 255) / 256, 256, 0, stream>>>(w1, w2, wT1, wT2);

    const float* hin = h;
    int T_in = 4096;
    for (int d = 0; d < 12; ++d) {
        int To = T_in >> 1;
        float* hn = (d & 1) ? H1 : H0;   // ping-pong; shrinking sizes always fit
        dim3 g1((To + 511) / 512, 16, 64);
        conv1_kernel<<<g1, 256, 0, stream>>>(hin, wT1, b1, N0, hn, R,
                                             T_in, To, d, log1pf((float)d));
        dim3 g2((To + 511) / 512, 8, 64);
        conv2_kernel<<<g2, 256, 0, stream>>>(R, wT2, b2, N0, rankfd, hn, out, To, d);
        hin = hn;
        T_in = To;
    }
}

// Round 2
// 4225.747 us; speedup vs baseline: 4.7208x; 4.7208x over previous
//
#include <hip/hip_runtime.h>
#include <cmath>
#include <cstdint>

// B=64, NH=256, T=4096, KS=5, STRIDE=2, DEPTH_VARIANT (Cin1=257), 12 depths.
// Strategy: both convs as bf16-MFMA GEMMs with hi/lo split (3 mfma) for fp32-level
// accuracy. Activations stored channels-last rows: [b][t] -> 1024B = 256 bf16 hi | 256 bf16 lo.
// l stored fp32 channels-last rows (1024B = 256 f32). conv2 writes h in-place over l.

typedef __attribute__((ext_vector_type(8))) __bf16 bf16x8;
typedef __attribute__((ext_vector_type(4))) float f32x4;

union U16B { uint4 u; bf16x8 b; };
__device__ __forceinline__ bf16x8 as_bf16x8(uint4 u) { U16B x; x.u = u; return x.b; }

__device__ __forceinline__ unsigned short bf_hi_bits(float x) {
    union { __bf16 b; unsigned short s; } u; u.b = (__bf16)x; return u.s;
}
__device__ __forceinline__ float bf_hi_f(float x) { return (float)(__bf16)x; }

#define MFMA(a, b, c) __builtin_amdgcn_mfma_f32_16x16x32_bf16(a, b, c, 0, 0, 0)

// ---------------- setup: finish_depth + stable argsort rank ----------------
__global__ void setup_kernel(const int* __restrict__ N0, int* __restrict__ rankfd) {
    __shared__ int fd_s[64];
    int b = threadIdx.x;
    int n = N0[b];
    int d = 0;
    while ((1 << (d + 1)) < n) ++d;   // first d with N0 <= 2^(d+1)
    fd_s[b] = d;
    __syncthreads();
    int myfd = fd_s[b];
    int r = 0;
    for (int i = 0; i < 64; ++i) {
        int f = fd_s[i];
        r += (f < myfd || (f == myfd && i < b)) ? 1 : 0;
    }
    rankfd[b] = r;
    rankfd[64 + b] = myfd;
}

// ------------- prepack: weights into MFMA A-fragment order, hi/lo ----------
// Layout: W*[chunk][ot][lane][j] flat; chunk = k*8+cc (c = cc*32 + (lane>>4)*8 + j),
// oc = ot*16 + (lane&15). conv1: OT=32 (512 oc), conv2: OT=16.
__global__ void prepack_kernel(const float* __restrict__ w1, const float* __restrict__ w2,
                               unsigned short* __restrict__ Whi1, unsigned short* __restrict__ Wlo1,
                               unsigned short* __restrict__ Whi2, unsigned short* __restrict__ Wlo2,
                               float* __restrict__ wd1, float* __restrict__ wsum1) {
    const int T1 = 40 * 32 * 512;
    const int T2 = 40 * 16 * 512;
    int id = blockIdx.x * 256 + threadIdx.x;
    if (id < T1) {
        int chunk = id >> 14;          // /(32*512)
        int rem = id & 16383;
        int ot = rem >> 9;
        int rem2 = rem & 511;
        int l = rem2 >> 3, j = rem2 & 7;
        int k = chunk >> 3, cc = chunk & 7;
        int oc = ot * 16 + (l & 15);
        int c = cc * 32 + (l >> 4) * 8 + j;
        float wv = w1[oc * 1285 + c * 5 + k];
        Whi1[id] = bf_hi_bits(wv);
        Wlo1[id] = bf_hi_bits(wv - bf_hi_f(wv));
    } else if (id < T1 + T2) {
        int base = id - T1;
        int chunk = base >> 13;        // /(16*512)
        int rem = base & 8191;
        int ot = rem >> 9;
        int rem2 = rem & 511;
        int l = rem2 >> 3, j = rem2 & 7;
        int k = chunk >> 3, cc = chunk & 7;
        int oc = ot * 16 + (l & 15);
        int c = cc * 32 + (l >> 4) * 8 + j;
        float wv = w2[oc * 1280 + c * 5 + k];
        Whi2[base] = bf_hi_bits(wv);
        Wlo2[base] = bf_hi_bits(wv - bf_hi_f(wv));
    } else if (id < T1 + T2 + 512) {
        int oc = id - T1 - T2;         // depth-channel weights (c = 256)
        float s = 0.f;
        for (int k = 0; k < 5; ++k) {
            float wv = w1[oc * 1285 + 1280 + k];
            wd1[oc * 5 + k] = wv;
            s += wv;
        }
        wsum1[oc] = s;
    }
}

// ---------------- conv1: lr = conv(hh_masked, w1, stride 2) ----------------
// Block 256 thr = 4 waves. Block: 256 ocs (y*256) x 32 t. Wave: 64 oc x 32 t
// (4 oc-tiles x 2 t-tiles of 16x16). K staged in two c-halves (LDS 34.8 KB).
__global__ __launch_bounds__(256, 2)
void conv1_kernel(const float* __restrict__ hraw, const char* __restrict__ Hin,
                  const unsigned short* __restrict__ Whi, const unsigned short* __restrict__ Wlo,
                  const float* __restrict__ b1, const float* __restrict__ wd1,
                  const float* __restrict__ wsum1, const int* __restrict__ N0,
                  float* __restrict__ Lout, char* __restrict__ Rout,
                  int T_in, int T_out, int depth, float logd) {
    __shared__ __align__(16) char smem[68 * 512];
    const int tid = threadIdx.x;
    const int w = tid >> 6, l = tid & 63;
    const int b = blockIdx.z;
    const int t0 = blockIdx.x * 32;
    const int n0 = N0[b];
    const int Nb = (n0 + (1 << depth) - 1) >> depth;   // input mask len
    const int Nn = (Nb + 1) >> 1;                      // output mask len

    if (t0 >= Nn) {
        if (blockIdx.y == 1) {   // zero r rows (conv2 reads them in its halo)
            int row = t0 + (tid >> 3);
            if (row < T_out) {
                char* rp = Rout + ((size_t)(b * T_out) + row) * 1024 + (tid & 7) * 128;
                uint4 z = make_uint4(0, 0, 0, 0);
#pragma unroll
                for (int qq = 0; qq < 8; ++qq) *(uint4*)(rp + qq * 16) = z;
            }
        }
        return;
    }

    f32x4 acc[4][2];
#pragma unroll
    for (int i = 0; i < 4; ++i)
#pragma unroll
        for (int j = 0; j < 2; ++j) acc[i][j] = f32x4{0.f, 0.f, 0.f, 0.f};

    const int base_p = 2 * t0 - 2;
    const int otg_base = blockIdx.y * 16 + w * 4;

    for (int half = 0; half < 2; ++half) {
        if (half) __syncthreads();
        // ---- stage this c-half (128 channels, hi+lo) for 68 input rows ----
        if (depth == 0) {
            // raw fp32 [B][256][4096] input, masked by N0
            const int cl = tid & 127;
            const int ro = tid >> 7;
            const float* hp = hraw + ((size_t)(b * 256 + half * 128 + cl)) * 4096;
            const int g = cl >> 3;
            const int boff = (cl & 7) * 2;
            for (int r0 = 0; r0 < 68; r0 += 2) {
                int r = r0 + ro;
                int p = base_p + r;
                float v = (p >= 0 && p < Nb) ? hp[p] : 0.f;
                float vh = bf_hi_f(v);
                int s = (r >> 1) + (r & 1) * 34;
                *(unsigned short*)(smem + s * 512 + ((g ^ (s & 7)) * 16) + boff) = bf_hi_bits(v);
                *(unsigned short*)(smem + s * 512 + (((16 + g) ^ (s & 7)) * 16) + boff) = bf_hi_bits(v - vh);
            }
        } else {
            // Hin rows: 1024B = 256 bf16 hi | 256 bf16 lo (pre-masked)
            const int seg = (l >> 4) & 1;   // 0=hi, 1=lo
            const int i16 = l & 15;
            const int g = seg * 16 + i16;
            for (int rb = w * 2 + (l >> 5); rb < 68; rb += 8) {
                int p = base_p + rb;
                uint4 v = make_uint4(0, 0, 0, 0);
                if (p >= 0 && p < T_in)
                    v = *(const uint4*)(Hin + ((size_t)(b * T_in) + p) * 1024 + seg * 512 + half * 256 + i16 * 16);
                int s = (rb >> 1) + (rb & 1) * 34;
                *(uint4*)(smem + s * 512 + ((g ^ (s & 7)) * 16)) = v;
            }
        }
        __syncthreads();
        // ---- K loop over this half: k_conv x 4 c-chunks of 32 ----
        for (int k = 0; k < 5; ++k) {
#pragma unroll
            for (int ccl = 0; ccl < 4; ++ccl) {
                const int chunk = k * 8 + half * 4 + ccl;
                bf16x8 Bh[2], Bl[2];
#pragma unroll
                for (int tt = 0; tt < 2; ++tt) {
                    int s = tt * 16 + (l & 15) + (k >> 1) + (k & 1) * 34;
                    int gh = ccl * 4 + (l >> 4);
                    Bh[tt] = as_bf16x8(*(const uint4*)(smem + s * 512 + ((gh ^ (s & 7)) * 16)));
                    Bl[tt] = as_bf16x8(*(const uint4*)(smem + s * 512 + (((16 + gh) ^ (s & 7)) * 16)));
                }
#pragma unroll
                for (int ot = 0; ot < 4; ++ot) {
                    size_t aoff = ((size_t)(chunk * 32 + otg_base + ot)) * 512 + l * 8;
                    bf16x8 Ah = as_bf16x8(*(const uint4*)(Whi + aoff));
                    bf16x8 Al = as_bf16x8(*(const uint4*)(Wlo + aoff));
#pragma unroll
                    for (int tt = 0; tt < 2; ++tt) {
                        acc[ot][tt] = MFMA(Ah, Bh[tt], acc[ot][tt]);
                        acc[ot][tt] = MFMA(Ah, Bl[tt], acc[ot][tt]);
                        acc[ot][tt] = MFMA(Al, Bh[tt], acc[ot][tt]);
                    }
                }
            }
        }
    }

    // ---- epilogue ----
    const int q = l >> 4;
    const int n = l & 15;
    const bool is_r = (blockIdx.y == 1);
#pragma unroll
    for (int ot = 0; ot < 4; ++ot) {
        const int ocg0 = (otg_base + ot) * 16 + q * 4;   // global oc (0..511)
        float4 bias = *(const float4*)(b1 + ocg0);
        float4 ws4 = *(const float4*)(wsum1 + ocg0);
#pragma unroll
        for (int tt = 0; tt < 2; ++tt) {
            int t = t0 + tt * 16 + n;
            if (t >= T_out) continue;
            float v0 = acc[ot][tt].x, v1 = acc[ot][tt].y, v2 = acc[ot][tt].z, v3 = acc[ot][tt].w;
            if (depth > 0) {   // depth-channel (constant log1p(depth), masked)
                if (t >= 1 && 2 * t + 2 < Nb) {
                    v0 += logd * ws4.x; v1 += logd * ws4.y;
                    v2 += logd * ws4.z; v3 += logd * ws4.w;
                } else {
                    float ind[5];
#pragma unroll
                    for (int k = 0; k < 5; ++k) {
                        int p = 2 * t + k - 2;
                        ind[k] = (p >= 0 && p < Nb) ? logd : 0.f;
                    }
                    float sv[4] = {0.f, 0.f, 0.f, 0.f};
#pragma unroll
                    for (int j = 0; j < 4; ++j)
#pragma unroll
                        for (int k = 0; k < 5; ++k) sv[j] += ind[k] * wd1[(ocg0 + j) * 5 + k];
                    v0 += sv[0]; v1 += sv[1]; v2 += sv[2]; v3 += sv[3];
                }
            }
            v0 += bias.x; v1 += bias.y; v2 += bias.z; v3 += bias.w;
            if (!is_r) {
                float4 o; o.x = v0; o.y = v1; o.z = v2; o.w = v3;
                *(float4*)(Lout + ((size_t)(b * T_out) + t) * 256 + ocg0) = o;
            } else {
                bool live = (t < Nn);
                float r0v = live ? fmaxf(v0, 0.f) : 0.f;
                float r1v = live ? fmaxf(v1, 0.f) : 0.f;
                float r2v = live ? fmaxf(v2, 0.f) : 0.f;
                float r3v = live ? fmaxf(v3, 0.f) : 0.f;
                int ocr = ocg0 - 256;
                char* rrow = Rout + ((size_t)(b * T_out) + t) * 1024;
                ushort4 H, L2;
                H.x = bf_hi_bits(r0v); L2.x = bf_hi_bits(r0v - bf_hi_f(r0v));
                H.y = bf_hi_bits(r1v); L2.y = bf_hi_bits(r1v - bf_hi_f(r1v));
                H.z = bf_hi_bits(r2v); L2.z = bf_hi_bits(r2v - bf_hi_f(r2v));
                H.w = bf_hi_bits(r3v); L2.w = bf_hi_bits(r3v - bf_hi_f(r3v));
                *(ushort4*)(rrow + ocr * 2) = H;
                *(ushort4*)(rrow + 512 + ocr * 2) = L2;
            }
        }
    }
}

// ------------- conv2: h = relu(l + conv(r, w2, 1) + b2), in-place ----------
__global__ __launch_bounds__(256, 3)
void conv2_kernel(const char* __restrict__ Rin,
                  const unsigned short* __restrict__ Whi, const unsigned short* __restrict__ Wlo,
                  const float* __restrict__ b2, const int* __restrict__ N0,
                  const int* __restrict__ rankfd, float* __restrict__ LH,
                  float* __restrict__ out, int T, int depth) {
    __shared__ __align__(16) char smem[2 * 36 * 512];   // hi plane | lo plane
    const int tid = threadIdx.x;
    const int w = tid >> 6, l = tid & 63;
    const int b = blockIdx.z;
    const int t0 = blockIdx.x * 32;
    const int n0 = N0[b];
    const int Nn = (n0 + (1 << (depth + 1)) - 1) >> (depth + 1);

    if (t0 >= Nn) {   // h rows are zero here; next conv1 stages them
        int row = t0 + (tid >> 3);
        if (row < T) {
            char* hp = (char*)LH + ((size_t)(b * T) + row) * 1024 + (tid & 7) * 128;
            uint4 z = make_uint4(0, 0, 0, 0);
#pragma unroll
            for (int qq = 0; qq < 8; ++qq) *(uint4*)(hp + qq * 16) = z;
        }
        return;
    }

    // ---- stage 36 rows of r (1024B each): lanes 0..31 hi, 32..63 lo ----
    {
        const int pl = l >> 5;
        const int g = l & 31;
        for (int r = w; r < 36; r += 4) {
            int p = t0 - 2 + r;
            uint4 v = make_uint4(0, 0, 0, 0);
            if (p >= 0 && p < T)
                v = *(const uint4*)(Rin + ((size_t)(b * T) + p) * 1024 + l * 16);
            *(uint4*)(smem + pl * 18432 + r * 512 + ((g ^ (r & 7)) * 16)) = v;
        }
    }
    __syncthreads();

    f32x4 acc[4][2];
#pragma unroll
    for (int i = 0; i < 4; ++i)
#pragma unroll
        for (int j = 0; j < 2; ++j) acc[i][j] = f32x4{0.f, 0.f, 0.f, 0.f};

    for (int k = 0; k < 5; ++k) {
#pragma unroll
        for (int cc = 0; cc < 8; ++cc) {
            const int chunk = k * 8 + cc;
            bf16x8 Bh[2], Bl[2];
#pragma unroll
            for (int tt = 0; tt < 2; ++tt) {
                int s = tt * 16 + (l & 15) + k;
                int gq = cc * 4 + (l >> 4);
                Bh[tt] = as_bf16x8(*(const uint4*)(smem + s * 512 + ((gq ^ (s & 7)) * 16)));
                Bl[tt] = as_bf16x8(*(const uint4*)(smem + 18432 + s * 512 + ((gq ^ (s & 7)) * 16)));
            }
#pragma unroll
            for (int ot = 0; ot < 4; ++ot) {
                size_t aoff = ((size_t)(chunk * 16 + w * 4 + ot)) * 512 + l * 8;
                bf16x8 Ah = as_bf16x8(*(const uint4*)(Whi + aoff));
                bf16x8 Al = as_bf16x8(*(const uint4*)(Wlo + aoff));
#pragma unroll
                for (int tt = 0; tt < 2; ++tt) {
                    acc[ot][tt] = MFMA(Ah, Bh[tt], acc[ot][tt]);
                    acc[ot][tt] = MFMA(Ah, Bl[tt], acc[ot][tt]);
                    acc[ot][tt] = MFMA(Al, Bh[tt], acc[ot][tt]);
                }
            }
        }
    }

    // ---- epilogue: read l (fp32), add, relu, mask; capture; then overwrite ----
    const int q = l >> 4;
    const int n = l & 15;
    const int rk = rankfd[b];
    const int fd = rankfd[64 + b];
    float vv[4][2][4];
#pragma unroll
    for (int ot = 0; ot < 4; ++ot) {
        const int ocg0 = (w * 4 + ot) * 16 + q * 4;
        float4 bias = *(const float4*)(b2 + ocg0);
#pragma unroll
        for (int tt = 0; tt < 2; ++tt) {
            int t = t0 + tt * 16 + n;
            float v0 = 0.f, v1 = 0.f, v2 = 0.f, v3 = 0.f;
            if (t < T && t < Nn) {
                float4 l4 = *(const float4*)(LH + ((size_t)(b * T) + t) * 256 + ocg0);
                v0 = fmaxf(acc[ot][tt].x + l4.x + bias.x, 0.f);
                v1 = fmaxf(acc[ot][tt].y + l4.y + bias.y, 0.f);
                v2 = fmaxf(acc[ot][tt].z + l4.z + bias.z, 0.f);
                v3 = fmaxf(acc[ot][tt].w + l4.w + bias.w, 0.f);
                if (t == 0 && depth == fd) {
                    float4 o; o.x = v0; o.y = v1; o.z = v2; o.w = v3;
                    *(float4*)(out + rk * 256 + ocg0) = o;
                }
            }
            vv[ot][tt][0] = v0; vv[ot][tt][1] = v1; vv[ot][tt][2] = v2; vv[ot][tt][3] = v3;
        }
    }
    __syncthreads();   // all l-reads done before in-place overwrite
#pragma unroll
    for (int ot = 0; ot < 4; ++ot) {
        const int ocg0 = (w * 4 + ot) * 16 + q * 4;
#pragma unroll
        for (int tt = 0; tt < 2; ++tt) {
            int t = t0 + tt * 16 + n;
            if (t >= T) continue;
            char* hrow = (char*)LH + ((size_t)(b * T) + t) * 1024;
            float v0 = vv[ot][tt][0], v1 = vv[ot][tt][1], v2 = vv[ot][tt][2], v3 = vv[ot][tt][3];
            ushort4 H, L2;
            H.x = bf_hi_bits(v0); L2.x = bf_hi_bits(v0 - bf_hi_f(v0));
            H.y = bf_hi_bits(v1); L2.y = bf_hi_bits(v1 - bf_hi_f(v1));
            H.z = bf_hi_bits(v2); L2.z = bf_hi_bits(v2 - bf_hi_f(v2));
            H.w = bf_hi_bits(v3); L2.w = bf_hi_bits(v3 - bf_hi_f(v3));
            *(ushort4*)(hrow + ocg0 * 2) = H;
            *(ushort4*)(hrow + 512 + ocg0 * 2) = L2;
        }
    }
}

// --------------------------------- launch ----------------------------------
extern "C" void kernel_launch(void* const* d_in, const int* in_sizes, int n_in,
                              void* d_out, int out_size, void* d_ws, size_t ws_size,
                              hipStream_t stream) {
    const float* h  = (const float*)d_in[0];
    const int*   N0 = (const int*)d_in[1];
    const float* w1 = (const float*)d_in[2];
    const float* b1 = (const float*)d_in[3];
    const float* w2 = (const float*)d_in[4];
    const float* b2 = (const float*)d_in[5];
    float* out = (float*)d_out;

    char* ws = (char*)d_ws;
    size_t off = 0;
    auto alloc = [&](size_t bytes) -> void* {
        void* p = ws + off;
        off = (off + bytes + 255) & ~(size_t)255;
        return p;
    };
    int* rankfd            = (int*)alloc(512);
    float* wd1             = (float*)alloc(512 * 5 * 4);
    float* wsum1           = (float*)alloc(512 * 4);
    unsigned short* Whi1   = (unsigned short*)alloc((size_t)655360 * 2);
    unsigned short* Wlo1   = (unsigned short*)alloc((size_t)655360 * 2);
    unsigned short* Whi2   = (unsigned short*)alloc((size_t)327680 * 2);
    unsigned short* Wlo2   = (unsigned short*)alloc((size_t)327680 * 2);
    float* P0              = (float*)alloc((size_t)64 * 1024 * 1024);   // odd depths (T<=1024)
    float* P1              = (float*)alloc((size_t)64 * 2048 * 1024);   // even depths (T<=2048)
    char* R                = (char*)alloc((size_t)64 * 2048 * 1024);
    (void)ws_size;

    setup_kernel<<<1, 64, 0, stream>>>(N0, rankfd);
    {
        int total = 655360 + 327680 + 512;
        prepack_kernel<<<(total + 255) / 256, 256, 0, stream>>>(w1, w2, Whi1, Wlo1, Whi2, Wlo2, wd1, wsum1);
    }

    int T_in = 4096;
    for (int d = 0; d < 12; ++d) {
        int To = T_in >> 1;
        float* LH = (d & 1) ? P0 : P1;
        const char* Hin = (const char*)((d & 1) ? P1 : P0);   // prev depth's h (d>=1)
        float logd = log1pf((float)d);
        dim3 g1((To + 31) / 32, 2, 64);
        conv1_kernel<<<g1, 256, 0, stream>>>(h, Hin, Whi1, Wlo1, b1, wd1, wsum1, N0,
                                             LH, R, T_in, To, d, logd);
        dim3 g2((To + 31) / 32, 1, 64);
        conv2_kernel<<<g2, 256, 0, stream>>>(R, Whi2, Wlo2, b2, N0, rankfd, LH, out, To, d);
        T_in = To;
    }
}

// Round 3
// 3297.114 us; speedup vs baseline: 6.0504x; 1.2817x over previous
//
#include <hip/hip_runtime.h>
#include <cmath>
#include <cstdint>

// B=64, NH=256, T=4096, KS=5, STRIDE=2, DEPTH_VARIANT (Cin1=257), 12 depths.
// bf16-MFMA GEMM formulation with hi/lo split (3 mfma) for fp32-level accuracy.
// Activations channels-last rows: [b][t] -> 1024B = 256 bf16 hi | 256 bf16 lo.
// l stored fp32 channels-last rows (1024B); conv2 overwrites them with h in place.
// Round 3: pre-transposed depth-0 input (coalesced), 64-wide t-tiles (6 MFMA per
// 16B weight load), <=35KB LDS staging passes -> 4 blocks/CU.

typedef __attribute__((ext_vector_type(8))) __bf16 bf16x8;
typedef __attribute__((ext_vector_type(4))) float f32x4;

union U16B { uint4 u; bf16x8 b; };
__device__ __forceinline__ bf16x8 as_bf16x8(uint4 u) { U16B x; x.u = u; return x.b; }

__device__ __forceinline__ unsigned short bf_hi_bits(float x) {
    union { __bf16 b; unsigned short s; } u; u.b = (__bf16)x; return u.s;
}
__device__ __forceinline__ float bf_hi_f(float x) { return (float)(__bf16)x; }

#define MFMA(a, b, c) __builtin_amdgcn_mfma_f32_16x16x32_bf16(a, b, c, 0, 0, 0)

// ---------------- setup: finish_depth + stable argsort rank ----------------
__global__ void setup_kernel(const int* __restrict__ N0, int* __restrict__ rankfd) {
    __shared__ int fd_s[64];
    int b = threadIdx.x;
    int n = N0[b];
    int d = 0;
    while ((1 << (d + 1)) < n) ++d;   // first d with N0 <= 2^(d+1)
    fd_s[b] = d;
    __syncthreads();
    int myfd = fd_s[b];
    int r = 0;
    for (int i = 0; i < 64; ++i) {
        int f = fd_s[i];
        r += (f < myfd || (f == myfd && i < b)) ? 1 : 0;
    }
    rankfd[b] = r;
    rankfd[64 + b] = myfd;
}

// ------------- prepack: weights into MFMA A-fragment order, hi/lo ----------
// W*[chunk][ot][lane][j]; chunk = k*8+cc (c = cc*32 + (lane>>4)*8 + j),
// oc = ot*16 + (lane&15). conv1: OT=32 (512 oc), conv2: OT=16.
__global__ void prepack_kernel(const float* __restrict__ w1, const float* __restrict__ w2,
                               unsigned short* __restrict__ Whi1, unsigned short* __restrict__ Wlo1,
                               unsigned short* __restrict__ Whi2, unsigned short* __restrict__ Wlo2,
                               float* __restrict__ wd1, float* __restrict__ wsum1) {
    const int T1 = 40 * 32 * 512;
    const int T2 = 40 * 16 * 512;
    int id = blockIdx.x * 256 + threadIdx.x;
    if (id < T1) {
        int chunk = id >> 14;
        int rem = id & 16383;
        int ot = rem >> 9;
        int rem2 = rem & 511;
        int l = rem2 >> 3, j = rem2 & 7;
        int k = chunk >> 3, cc = chunk & 7;
        int oc = ot * 16 + (l & 15);
        int c = cc * 32 + (l >> 4) * 8 + j;
        float wv = w1[oc * 1285 + c * 5 + k];
        Whi1[id] = bf_hi_bits(wv);
        Wlo1[id] = bf_hi_bits(wv - bf_hi_f(wv));
    } else if (id < T1 + T2) {
        int base = id - T1;
        int chunk = base >> 13;
        int rem = base & 8191;
        int ot = rem >> 9;
        int rem2 = rem & 511;
        int l = rem2 >> 3, j = rem2 & 7;
        int k = chunk >> 3, cc = chunk & 7;
        int oc = ot * 16 + (l & 15);
        int c = cc * 32 + (l >> 4) * 8 + j;
        float wv = w2[oc * 1280 + c * 5 + k];
        Whi2[base] = bf_hi_bits(wv);
        Wlo2[base] = bf_hi_bits(wv - bf_hi_f(wv));
    } else if (id < T1 + T2 + 512) {
        int oc = id - T1 - T2;         // depth-channel weights (c = 256)
        float s = 0.f;
        for (int k = 0; k < 5; ++k) {
            float wv = w1[oc * 1285 + 1280 + k];
            wd1[oc * 5 + k] = wv;
            s += wv;
        }
        wsum1[oc] = s;
    }
}

// ---- transpose h [B][256][4096] fp32 (masked) -> channels-last hi/lo rows ----
// Block: 64 channels x 128 t. Coalesced float4 reads, LDS transpose, coalesced
// 16B writes. LDS layout: [plane][c][t] with c-stride 140 shorts (280B).
__global__ __launch_bounds__(256, 2)
void transpose_kernel(const float* __restrict__ h, const int* __restrict__ N0,
                      char* __restrict__ H) {
    __shared__ unsigned short sm[2 * 64 * 140];   // 35840 B
    const int tid = threadIdx.x;
    const int b = blockIdx.z;
    const int c0 = blockIdx.y * 64;
    const int t0 = blockIdx.x * 128;
    const int n0 = N0[b];
    const int lane32 = tid & 31;
    // read phase
    for (int it = 0; it < 8; ++it) {
        int cl = (tid >> 5) * 8 + it;
        const float* src = h + ((size_t)(b * 256 + c0 + cl)) * 4096 + t0 + lane32 * 4;
        float4 v = *(const float4*)src;
        int gt = t0 + lane32 * 4;
        float f[4] = {v.x, v.y, v.z, v.w};
        ushort4 hi, lo;
        unsigned short* hp = &hi.x;
        unsigned short* lp = &lo.x;
#pragma unroll
        for (int e = 0; e < 4; ++e) {
            float x = (gt + e < n0) ? f[e] : 0.f;
            float xh = bf_hi_f(x);
            hp[e] = bf_hi_bits(x);
            lp[e] = bf_hi_bits(x - xh);
        }
        *(ushort4*)(&sm[cl * 140 + lane32 * 4]) = hi;
        *(ushort4*)(&sm[8960 + cl * 140 + lane32 * 4]) = lo;
    }
    __syncthreads();
    // write phase
    const int sub = tid & 7;
    const int rowp = tid >> 3;
    for (int rep = 0; rep < 8; ++rep) {
        int idx = rowp + 32 * rep;      // 0..255
        int tl = idx >> 1;
        int plane = idx & 1;
        union { unsigned short s[8]; uint4 u; } pk;
#pragma unroll
        for (int j = 0; j < 8; ++j)
            pk.s[j] = sm[plane * 8960 + (sub * 8 + j) * 140 + tl];
        char* dst = H + ((size_t)(b * 4096) + t0 + tl) * 1024 + plane * 512 + c0 * 2 + sub * 16;
        *(uint4*)dst = pk.u;
    }
}

// ---------------- conv1: lr = conv(hh_masked, w1, stride 2) ----------------
// Block 256 thr = 4 waves; block tile 256 oc (y in {0,1}) x 64 t; wave 64oc x 64t.
// K staged in 4 c-quarters (64 ch hi+lo, 132 rows x 256B = 33.8 KB LDS).
__global__ __launch_bounds__(256, 2)
void conv1_kernel(const char* __restrict__ Hin,
                  const unsigned short* __restrict__ Whi, const unsigned short* __restrict__ Wlo,
                  const float* __restrict__ b1, const float* __restrict__ wd1,
                  const float* __restrict__ wsum1, const int* __restrict__ N0,
                  float* __restrict__ Lout, char* __restrict__ Rout,
                  int T_in, int T_out, int depth, float logd) {
    __shared__ __align__(16) char smem[132 * 256];
    const int tid = threadIdx.x;
    const int w = tid >> 6, l = tid & 63;
    const int b = blockIdx.z;
    const int t0 = blockIdx.x * 64;
    const int n0 = N0[b];
    const int Nb = (n0 + (1 << depth) - 1) >> depth;   // input mask len
    const int Nn = (Nb + 1) >> 1;                      // output mask len

    if (t0 >= Nn) {
        if (blockIdx.y == 1) {   // zero r rows (conv2 reads them in its halo)
            int row = t0 + (tid >> 2);
            if (row < T_out) {
                char* rp = Rout + ((size_t)(b * T_out) + row) * 1024 + (tid & 3) * 256;
                uint4 z = make_uint4(0, 0, 0, 0);
#pragma unroll
                for (int qq = 0; qq < 16; ++qq) *(uint4*)(rp + qq * 16) = z;
            }
        }
        return;
    }

    f32x4 acc[4][4];
#pragma unroll
    for (int i = 0; i < 4; ++i)
#pragma unroll
        for (int j = 0; j < 4; ++j) acc[i][j] = f32x4{0.f, 0.f, 0.f, 0.f};

    const int base_p = 2 * t0 - 2;
    const int otg_base = blockIdx.y * 16 + w * 4;

    // staging decomposition: 16 chunks/row (8 hi + 8 lo of this quarter)
    const int sg_g8 = l & 7;
    const int sg_seg = (l >> 3) & 1;
    const int sg_rb0 = tid >> 4;        // 0..15

#pragma unroll 1
    for (int q0 = 0; q0 < 4; ++q0) {
        if (q0) __syncthreads();
        for (int rb = sg_rb0; rb < 132; rb += 16) {
            int p = base_p + rb;
            uint4 v = make_uint4(0, 0, 0, 0);
            if (p >= 0 && p < T_in)
                v = *(const uint4*)(Hin + ((size_t)(b * T_in) + p) * 1024 + sg_seg * 512 + q0 * 128 + sg_g8 * 16);
            int s = (rb >> 1) + (rb & 1) * 66;   // even/odd split for stride-2
            int phys = (sg_g8 ^ (s & 7)) | (sg_seg << 3);
            *(uint4*)(smem + s * 256 + phys * 16) = v;
        }
        __syncthreads();
#pragma unroll
        for (int k = 0; k < 5; ++k) {
#pragma unroll
            for (int ccl = 0; ccl < 2; ++ccl) {
                const int chunk = k * 8 + q0 * 2 + ccl;
                bf16x8 Bh[4], Bl[4];
#pragma unroll
                for (int tt = 0; tt < 4; ++tt) {
                    int s = tt * 16 + (l & 15) + (k >> 1) + (k & 1) * 66;
                    int gB = ccl * 4 + (l >> 4);
                    int ph = gB ^ (s & 7);
                    Bh[tt] = as_bf16x8(*(const uint4*)(smem + s * 256 + ph * 16));
                    Bl[tt] = as_bf16x8(*(const uint4*)(smem + s * 256 + (ph | 8) * 16));
                }
#pragma unroll
                for (int ot = 0; ot < 4; ++ot) {
                    size_t aoff = ((size_t)(chunk * 32 + otg_base + ot)) * 512 + l * 8;
                    bf16x8 Ah = as_bf16x8(*(const uint4*)(Whi + aoff));
                    bf16x8 Al = as_bf16x8(*(const uint4*)(Wlo + aoff));
#pragma unroll
                    for (int tt = 0; tt < 4; ++tt) {
                        acc[ot][tt] = MFMA(Ah, Bh[tt], acc[ot][tt]);
                        acc[ot][tt] = MFMA(Ah, Bl[tt], acc[ot][tt]);
                        acc[ot][tt] = MFMA(Al, Bh[tt], acc[ot][tt]);
                    }
                }
            }
        }
    }

    // ---- epilogue ----
    const int q = l >> 4;
    const int n = l & 15;
    const bool is_r = (blockIdx.y == 1);
#pragma unroll
    for (int ot = 0; ot < 4; ++ot) {
        const int ocg0 = (otg_base + ot) * 16 + q * 4;   // global oc (0..511)
        float4 bias = *(const float4*)(b1 + ocg0);
        float4 ws4 = *(const float4*)(wsum1 + ocg0);
#pragma unroll
        for (int tt = 0; tt < 4; ++tt) {
            int t = t0 + tt * 16 + n;
            if (t >= T_out) continue;
            float v0 = acc[ot][tt].x, v1 = acc[ot][tt].y, v2 = acc[ot][tt].z, v3 = acc[ot][tt].w;
            if (depth > 0) {   // depth channel (constant log1p(depth), masked)
                if (t >= 1 && 2 * t + 2 < Nb) {
                    v0 += logd * ws4.x; v1 += logd * ws4.y;
                    v2 += logd * ws4.z; v3 += logd * ws4.w;
                } else {
                    float ind[5];
#pragma unroll
                    for (int k = 0; k < 5; ++k) {
                        int p = 2 * t + k - 2;
                        ind[k] = (p >= 0 && p < Nb) ? logd : 0.f;
                    }
                    float sv[4] = {0.f, 0.f, 0.f, 0.f};
#pragma unroll
                    for (int j = 0; j < 4; ++j)
#pragma unroll
                        for (int k = 0; k < 5; ++k) sv[j] += ind[k] * wd1[(ocg0 + j) * 5 + k];
                    v0 += sv[0]; v1 += sv[1]; v2 += sv[2]; v3 += sv[3];
                }
            }
            v0 += bias.x; v1 += bias.y; v2 += bias.z; v3 += bias.w;
            if (!is_r) {
                float4 o; o.x = v0; o.y = v1; o.z = v2; o.w = v3;
                *(float4*)(Lout + ((size_t)(b * T_out) + t) * 256 + ocg0) = o;
            } else {
                bool live = (t < Nn);
                float r0v = live ? fmaxf(v0, 0.f) : 0.f;
                float r1v = live ? fmaxf(v1, 0.f) : 0.f;
                float r2v = live ? fmaxf(v2, 0.f) : 0.f;
                float r3v = live ? fmaxf(v3, 0.f) : 0.f;
                int ocr = ocg0 - 256;
                char* rrow = Rout + ((size_t)(b * T_out) + t) * 1024;
                ushort4 H, L2;
                H.x = bf_hi_bits(r0v); L2.x = bf_hi_bits(r0v - bf_hi_f(r0v));
                H.y = bf_hi_bits(r1v); L2.y = bf_hi_bits(r1v - bf_hi_f(r1v));
                H.z = bf_hi_bits(r2v); L2.z = bf_hi_bits(r2v - bf_hi_f(r2v));
                H.w = bf_hi_bits(r3v); L2.w = bf_hi_bits(r3v - bf_hi_f(r3v));
                *(ushort4*)(rrow + ocr * 2) = H;
                *(ushort4*)(rrow + 512 + ocr * 2) = L2;
            }
        }
    }
}

// ------------- conv2: h = relu(l + conv(r, w2, 1) + b2), in-place ----------
// Block 256 oc x 64 t; K staged in 2 c-halves (68 rows x 512B = 34.8 KB LDS).
__global__ __launch_bounds__(256, 2)
void conv2_kernel(const char* __restrict__ Rin,
                  const unsigned short* __restrict__ Whi, const unsigned short* __restrict__ Wlo,
                  const float* __restrict__ b2, const int* __restrict__ N0,
                  const int* __restrict__ rankfd, float* __restrict__ LH,
                  float* __restrict__ out, int T, int depth) {
    __shared__ __align__(16) char smem[68 * 512];
    const int tid = threadIdx.x;
    const int w = tid >> 6, l = tid & 63;
    const int b = blockIdx.z;
    const int t0 = blockIdx.x * 64;
    const int n0 = N0[b];
    const int Nn = (n0 + (1 << (depth + 1)) - 1) >> (depth + 1);

    if (t0 >= Nn) {   // h rows are zero here; next conv1 reads them
        int row = t0 + (tid >> 2);
        if (row < T) {
            char* hp = (char*)LH + ((size_t)(b * T) + row) * 1024 + (tid & 3) * 256;
            uint4 z = make_uint4(0, 0, 0, 0);
#pragma unroll
            for (int qq = 0; qq < 16; ++qq) *(uint4*)(hp + qq * 16) = z;
        }
        return;
    }

    f32x4 acc[4][4];
#pragma unroll
    for (int i = 0; i < 4; ++i)
#pragma unroll
        for (int j = 0; j < 4; ++j) acc[i][j] = f32x4{0.f, 0.f, 0.f, 0.f};

    const int sg_g16 = l & 15;
    const int sg_seg = (l >> 4) & 1;
    const int sg_rb0 = w * 2 + (l >> 5);

#pragma unroll 1
    for (int hf = 0; hf < 2; ++hf) {
        if (hf) __syncthreads();
        for (int rb = sg_rb0; rb < 68; rb += 8) {
            int p = t0 - 2 + rb;
            uint4 v = make_uint4(0, 0, 0, 0);
            if (p >= 0 && p < T)
                v = *(const uint4*)(Rin + ((size_t)(b * T) + p) * 1024 + sg_seg * 512 + hf * 256 + sg_g16 * 16);
            int phys = (sg_g16 ^ (rb & 7)) | (sg_seg << 4);
            *(uint4*)(smem + rb * 512 + phys * 16) = v;
        }
        __syncthreads();
#pragma unroll
        for (int k = 0; k < 5; ++k) {
#pragma unroll
            for (int cc = 0; cc < 4; ++cc) {
                const int chunk = k * 8 + hf * 4 + cc;
                bf16x8 Bh[4], Bl[4];
#pragma unroll
                for (int tt = 0; tt < 4; ++tt) {
                    int s = tt * 16 + (l & 15) + k;
                    int gq = cc * 4 + (l >> 4);
                    int ph = gq ^ (s & 7);
                    Bh[tt] = as_bf16x8(*(const uint4*)(smem + s * 512 + ph * 16));
                    Bl[tt] = as_bf16x8(*(const uint4*)(smem + s * 512 + (ph | 16) * 16));
                }
#pragma unroll
                for (int ot = 0; ot < 4; ++ot) {
                    size_t aoff = ((size_t)(chunk * 16 + w * 4 + ot)) * 512 + l * 8;
                    bf16x8 Ah = as_bf16x8(*(const uint4*)(Whi + aoff));
                    bf16x8 Al = as_bf16x8(*(const uint4*)(Wlo + aoff));
#pragma unroll
                    for (int tt = 0; tt < 4; ++tt) {
                        acc[ot][tt] = MFMA(Ah, Bh[tt], acc[ot][tt]);
                        acc[ot][tt] = MFMA(Ah, Bl[tt], acc[ot][tt]);
                        acc[ot][tt] = MFMA(Al, Bh[tt], acc[ot][tt]);
                    }
                }
            }
        }
    }

    // ---- epilogue: l + acc + bias, relu, mask, capture; barrier; in-place h ----
    const int q = l >> 4;
    const int n = l & 15;
    const int rk = rankfd[b];
    const int fd = rankfd[64 + b];
#pragma unroll
    for (int ot = 0; ot < 4; ++ot) {
        const int ocg0 = (w * 4 + ot) * 16 + q * 4;
        float4 bias = *(const float4*)(b2 + ocg0);
#pragma unroll
        for (int tt = 0; tt < 4; ++tt) {
            int t = t0 + tt * 16 + n;
            float v0 = 0.f, v1 = 0.f, v2 = 0.f, v3 = 0.f;
            if (t < T && t < Nn) {
                float4 l4 = *(const float4*)(LH + ((size_t)(b * T) + t) * 256 + ocg0);
                v0 = fmaxf(acc[ot][tt].x + l4.x + bias.x, 0.f);
                v1 = fmaxf(acc[ot][tt].y + l4.y + bias.y, 0.f);
                v2 = fmaxf(acc[ot][tt].z + l4.z + bias.z, 0.f);
                v3 = fmaxf(acc[ot][tt].w + l4.w + bias.w, 0.f);
                if (t == 0 && depth == fd) {
                    float4 o; o.x = v0; o.y = v1; o.z = v2; o.w = v3;
                    *(float4*)(out + rk * 256 + ocg0) = o;
                }
            }
            acc[ot][tt] = f32x4{v0, v1, v2, v3};   // reuse acc as value buffer
        }
    }
    __syncthreads();   // all l-reads complete before in-place overwrite
#pragma unroll
    for (int ot = 0; ot < 4; ++ot) {
        const int ocg0 = (w * 4 + ot) * 16 + q * 4;
#pragma unroll
        for (int tt = 0; tt < 4; ++tt) {
            int t = t0 + tt * 16 + n;
            if (t >= T) continue;
            char* hrow = (char*)LH + ((size_t)(b * T) + t) * 1024;
            float v0 = acc[ot][tt].x, v1 = acc[ot][tt].y, v2 = acc[ot][tt].z, v3 = acc[ot][tt].w;
            ushort4 H, L2;
            H.x = bf_hi_bits(v0); L2.x = bf_hi_bits(v0 - bf_hi_f(v0));
            H.y = bf_hi_bits(v1); L2.y = bf_hi_bits(v1 - bf_hi_f(v1));
            H.z = bf_hi_bits(v2); L2.z = bf_hi_bits(v2 - bf_hi_f(v2));
            H.w = bf_hi_bits(v3); L2.w = bf_hi_bits(v3 - bf_hi_f(v3));
            *(ushort4*)(hrow + ocg0 * 2) = H;
            *(ushort4*)(hrow + 512 + ocg0 * 2) = L2;
        }
    }
}

// --------------------------------- launch ----------------------------------
extern "C" void kernel_launch(void* const* d_in, const int* in_sizes, int n_in,
                              void* d_out, int out_size, void* d_ws, size_t ws_size,
                              hipStream_t stream) {
    const float* h  = (const float*)d_in[0];
    const int*   N0 = (const int*)d_in[1];
    const float* w1 = (const float*)d_in[2];
    const float* b1 = (const float*)d_in[3];
    const float* w2 = (const float*)d_in[4];
    const float* b2 = (const float*)d_in[5];
    float* out = (float*)d_out;

    char* ws = (char*)d_ws;
    size_t off = 0;
    auto alloc = [&](size_t bytes) -> void* {
        void* p = ws + off;
        off = (off + bytes + 255) & ~(size_t)255;
        return p;
    };
    int* rankfd            = (int*)alloc(512);
    float* wd1             = (float*)alloc(512 * 5 * 4);
    float* wsum1           = (float*)alloc(512 * 4);
    unsigned short* Whi1   = (unsigned short*)alloc((size_t)655360 * 2);
    unsigned short* Wlo1   = (unsigned short*)alloc((size_t)655360 * 2);
    unsigned short* Whi2   = (unsigned short*)alloc((size_t)327680 * 2);
    unsigned short* Wlo2   = (unsigned short*)alloc((size_t)327680 * 2);
    float* P1              = (float*)alloc((size_t)64 * 2048 * 1024);   // even-depth h rows
    char*  H4096           = (char*)alloc((size_t)64 * 4096 * 1024);   // depth-0 input
    float* P0              = (float*)H4096;   // alias: H4096 dead after d0 conv1
    char*  R               = (char*)alloc((size_t)64 * 2048 * 1024);
    (void)ws_size;

    setup_kernel<<<1, 64, 0, stream>>>(N0, rankfd);
    {
        int total = 655360 + 327680 + 512;
        prepack_kernel<<<(total + 255) / 256, 256, 0, stream>>>(w1, w2, Whi1, Wlo1, Whi2, Wlo2, wd1, wsum1);
    }
    transpose_kernel<<<dim3(32, 4, 64), 256, 0, stream>>>(h, N0, H4096);

    int T_in = 4096;
    for (int d = 0; d < 12; ++d) {
        int To = T_in >> 1;
        float* LH = (d & 1) ? P0 : P1;
        const char* Hin = (d == 0) ? (const char*)H4096 : (const char*)((d & 1) ? P1 : P0);
        float logd = log1pf((float)d);
        dim3 g1((To + 63) / 64, 2, 64);
        conv1_kernel<<<g1, 256, 0, stream>>>(Hin, Whi1, Wlo1, b1, wd1, wsum1, N0,
                                             LH, R, T_in, To, d, logd);
        dim3 g2((To + 63) / 64, 1, 64);
        conv2_kernel<<<g2, 256, 0, stream>>>(R, Whi2, Wlo2, b2, N0, rankfd, LH, out, To, d);
        T_in = To;
    }
}

// Round 4
// 2847.251 us; speedup vs baseline: 7.0063x; 1.1580x over previous
//
#include <hip/hip_runtime.h>
#include <cmath>
#include <cstdint>

// B=64, NH=256, T=4096, KS=5, STRIDE=2, DEPTH_VARIANT (Cin1=257), 12 depths.
// bf16-MFMA GEMM formulation with hi/lo split (3 mfma) for fp32-level accuracy.
// Activations channels-last rows: [b][t] -> 1024B = 256 bf16 hi | 256 bf16 lo.
// l stored fp32 channels-last rows (1024B); conv2 overwrites them with h in place.
// Round 4: occupancy experiment — launch_bounds(256,4) => 4 blocks/CU
// (LDS 33.8/34.8 KB x4 fits 160 KB; VGPR was 68, cap 128). Wave-level overlap
// (m114) is the measured latency-hiding mechanism on gfx950.

typedef __attribute__((ext_vector_type(8))) __bf16 bf16x8;
typedef __attribute__((ext_vector_type(4))) float f32x4;

union U16B { uint4 u; bf16x8 b; };
__device__ __forceinline__ bf16x8 as_bf16x8(uint4 u) { U16B x; x.u = u; return x.b; }

__device__ __forceinline__ unsigned short bf_hi_bits(float x) {
    union { __bf16 b; unsigned short s; } u; u.b = (__bf16)x; return u.s;
}
__device__ __forceinline__ float bf_hi_f(float x) { return (float)(__bf16)x; }

#define MFMA(a, b, c) __builtin_amdgcn_mfma_f32_16x16x32_bf16(a, b, c, 0, 0, 0)

// ---------------- setup: finish_depth + stable argsort rank ----------------
__global__ void setup_kernel(const int* __restrict__ N0, int* __restrict__ rankfd) {
    __shared__ int fd_s[64];
    int b = threadIdx.x;
    int n = N0[b];
    int d = 0;
    while ((1 << (d + 1)) < n) ++d;   // first d with N0 <= 2^(d+1)
    fd_s[b] = d;
    __syncthreads();
    int myfd = fd_s[b];
    int r = 0;
    for (int i = 0; i < 64; ++i) {
        int f = fd_s[i];
        r += (f < myfd || (f == myfd && i < b)) ? 1 : 0;
    }
    rankfd[b] = r;
    rankfd[64 + b] = myfd;
}

// ------------- prepack: weights into MFMA A-fragment order, hi/lo ----------
// W*[chunk][ot][lane][j]; chunk = k*8+cc (c = cc*32 + (lane>>4)*8 + j),
// oc = ot*16 + (lane&15). conv1: OT=32 (512 oc), conv2: OT=16.
__global__ void prepack_kernel(const float* __restrict__ w1, const float* __restrict__ w2,
                               unsigned short* __restrict__ Whi1, unsigned short* __restrict__ Wlo1,
                               unsigned short* __restrict__ Whi2, unsigned short* __restrict__ Wlo2,
                               float* __restrict__ wd1, float* __restrict__ wsum1) {
    const int T1 = 40 * 32 * 512;
    const int T2 = 40 * 16 * 512;
    int id = blockIdx.x * 256 + threadIdx.x;
    if (id < T1) {
        int chunk = id >> 14;
        int rem = id & 16383;
        int ot = rem >> 9;
        int rem2 = rem & 511;
        int l = rem2 >> 3, j = rem2 & 7;
        int k = chunk >> 3, cc = chunk & 7;
        int oc = ot * 16 + (l & 15);
        int c = cc * 32 + (l >> 4) * 8 + j;
        float wv = w1[oc * 1285 + c * 5 + k];
        Whi1[id] = bf_hi_bits(wv);
        Wlo1[id] = bf_hi_bits(wv - bf_hi_f(wv));
    } else if (id < T1 + T2) {
        int base = id - T1;
        int chunk = base >> 13;
        int rem = base & 8191;
        int ot = rem >> 9;
        int rem2 = rem & 511;
        int l = rem2 >> 3, j = rem2 & 7;
        int k = chunk >> 3, cc = chunk & 7;
        int oc = ot * 16 + (l & 15);
        int c = cc * 32 + (l >> 4) * 8 + j;
        float wv = w2[oc * 1280 + c * 5 + k];
        Whi2[base] = bf_hi_bits(wv);
        Wlo2[base] = bf_hi_bits(wv - bf_hi_f(wv));
    } else if (id < T1 + T2 + 512) {
        int oc = id - T1 - T2;         // depth-channel weights (c = 256)
        float s = 0.f;
        for (int k = 0; k < 5; ++k) {
            float wv = w1[oc * 1285 + 1280 + k];
            wd1[oc * 5 + k] = wv;
            s += wv;
        }
        wsum1[oc] = s;
    }
}

// ---- transpose h [B][256][4096] fp32 (masked) -> channels-last hi/lo rows ----
__global__ __launch_bounds__(256, 4)
void transpose_kernel(const float* __restrict__ h, const int* __restrict__ N0,
                      char* __restrict__ H) {
    __shared__ unsigned short sm[2 * 64 * 140];   // 35840 B
    const int tid = threadIdx.x;
    const int b = blockIdx.z;
    const int c0 = blockIdx.y * 64;
    const int t0 = blockIdx.x * 128;
    const int n0 = N0[b];
    const int lane32 = tid & 31;
    // read phase
    for (int it = 0; it < 8; ++it) {
        int cl = (tid >> 5) * 8 + it;
        const float* src = h + ((size_t)(b * 256 + c0 + cl)) * 4096 + t0 + lane32 * 4;
        float4 v = *(const float4*)src;
        int gt = t0 + lane32 * 4;
        float f[4] = {v.x, v.y, v.z, v.w};
        ushort4 hi, lo;
        unsigned short* hp = &hi.x;
        unsigned short* lp = &lo.x;
#pragma unroll
        for (int e = 0; e < 4; ++e) {
            float x = (gt + e < n0) ? f[e] : 0.f;
            float xh = bf_hi_f(x);
            hp[e] = bf_hi_bits(x);
            lp[e] = bf_hi_bits(x - xh);
        }
        *(ushort4*)(&sm[cl * 140 + lane32 * 4]) = hi;
        *(ushort4*)(&sm[8960 + cl * 140 + lane32 * 4]) = lo;
    }
    __syncthreads();
    // write phase
    const int sub = tid & 7;
    const int rowp = tid >> 3;
    for (int rep = 0; rep < 8; ++rep) {
        int idx = rowp + 32 * rep;      // 0..255
        int tl = idx >> 1;
        int plane = idx & 1;
        union { unsigned short s[8]; uint4 u; } pk;
#pragma unroll
        for (int j = 0; j < 8; ++j)
            pk.s[j] = sm[plane * 8960 + (sub * 8 + j) * 140 + tl];
        char* dst = H + ((size_t)(b * 4096) + t0 + tl) * 1024 + plane * 512 + c0 * 2 + sub * 16;
        *(uint4*)dst = pk.u;
    }
}

// ---------------- conv1: lr = conv(hh_masked, w1, stride 2) ----------------
// Block 256 thr = 4 waves; block tile 256 oc (y in {0,1}) x 64 t; wave 64oc x 64t.
// K staged in 4 c-quarters (64 ch hi+lo, 132 rows x 256B = 33.8 KB LDS).
__global__ __launch_bounds__(256, 4)
void conv1_kernel(const char* __restrict__ Hin,
                  const unsigned short* __restrict__ Whi, const unsigned short* __restrict__ Wlo,
                  const float* __restrict__ b1, const float* __restrict__ wd1,
                  const float* __restrict__ wsum1, const int* __restrict__ N0,
                  float* __restrict__ Lout, char* __restrict__ Rout,
                  int T_in, int T_out, int depth, float logd) {
    __shared__ __align__(16) char smem[132 * 256];
    const int tid = threadIdx.x;
    const int w = tid >> 6, l = tid & 63;
    const int b = blockIdx.z;
    const int t0 = blockIdx.x * 64;
    const int n0 = N0[b];
    const int Nb = (n0 + (1 << depth) - 1) >> depth;   // input mask len
    const int Nn = (Nb + 1) >> 1;                      // output mask len

    if (t0 >= Nn) {
        if (blockIdx.y == 1) {   // zero r rows (conv2 reads them in its halo)
            int row = t0 + (tid >> 2);
            if (row < T_out) {
                char* rp = Rout + ((size_t)(b * T_out) + row) * 1024 + (tid & 3) * 256;
                uint4 z = make_uint4(0, 0, 0, 0);
#pragma unroll
                for (int qq = 0; qq < 16; ++qq) *(uint4*)(rp + qq * 16) = z;
            }
        }
        return;
    }

    f32x4 acc[4][4];
#pragma unroll
    for (int i = 0; i < 4; ++i)
#pragma unroll
        for (int j = 0; j < 4; ++j) acc[i][j] = f32x4{0.f, 0.f, 0.f, 0.f};

    const int base_p = 2 * t0 - 2;
    const int otg_base = blockIdx.y * 16 + w * 4;

    // staging decomposition: 16 chunks/row (8 hi + 8 lo of this quarter)
    const int sg_g8 = l & 7;
    const int sg_seg = (l >> 3) & 1;
    const int sg_rb0 = tid >> 4;        // 0..15

#pragma unroll 1
    for (int q0 = 0; q0 < 4; ++q0) {
        if (q0) __syncthreads();
        for (int rb = sg_rb0; rb < 132; rb += 16) {
            int p = base_p + rb;
            uint4 v = make_uint4(0, 0, 0, 0);
            if (p >= 0 && p < T_in)
                v = *(const uint4*)(Hin + ((size_t)(b * T_in) + p) * 1024 + sg_seg * 512 + q0 * 128 + sg_g8 * 16);
            int s = (rb >> 1) + (rb & 1) * 66;   // even/odd split for stride-2
            int phys = (sg_g8 ^ (s & 7)) | (sg_seg << 3);
            *(uint4*)(smem + s * 256 + phys * 16) = v;
        }
        __syncthreads();
#pragma unroll
        for (int k = 0; k < 5; ++k) {
#pragma unroll
            for (int ccl = 0; ccl < 2; ++ccl) {
                const int chunk = k * 8 + q0 * 2 + ccl;
                bf16x8 Bh[4], Bl[4];
#pragma unroll
                for (int tt = 0; tt < 4; ++tt) {
                    int s = tt * 16 + (l & 15) + (k >> 1) + (k & 1) * 66;
                    int gB = ccl * 4 + (l >> 4);
                    int ph = gB ^ (s & 7);
                    Bh[tt] = as_bf16x8(*(const uint4*)(smem + s * 256 + ph * 16));
                    Bl[tt] = as_bf16x8(*(const uint4*)(smem + s * 256 + (ph | 8) * 16));
                }
#pragma unroll
                for (int ot = 0; ot < 4; ++ot) {
                    size_t aoff = ((size_t)(chunk * 32 + otg_base + ot)) * 512 + l * 8;
                    bf16x8 Ah = as_bf16x8(*(const uint4*)(Whi + aoff));
                    bf16x8 Al = as_bf16x8(*(const uint4*)(Wlo + aoff));
#pragma unroll
                    for (int tt = 0; tt < 4; ++tt) {
                        acc[ot][tt] = MFMA(Ah, Bh[tt], acc[ot][tt]);
                        acc[ot][tt] = MFMA(Ah, Bl[tt], acc[ot][tt]);
                        acc[ot][tt] = MFMA(Al, Bh[tt], acc[ot][tt]);
                    }
                }
            }
        }
    }

    // ---- epilogue ----
    const int q = l >> 4;
    const int n = l & 15;
    const bool is_r = (blockIdx.y == 1);
#pragma unroll
    for (int ot = 0; ot < 4; ++ot) {
        const int ocg0 = (otg_base + ot) * 16 + q * 4;   // global oc (0..511)
        float4 bias = *(const float4*)(b1 + ocg0);
        float4 ws4 = *(const float4*)(wsum1 + ocg0);
#pragma unroll
        for (int tt = 0; tt < 4; ++tt) {
            int t = t0 + tt * 16 + n;
            if (t >= T_out) continue;
            float v0 = acc[ot][tt].x, v1 = acc[ot][tt].y, v2 = acc[ot][tt].z, v3 = acc[ot][tt].w;
            if (depth > 0) {   // depth channel (constant log1p(depth), masked)
                if (t >= 1 && 2 * t + 2 < Nb) {
                    v0 += logd * ws4.x; v1 += logd * ws4.y;
                    v2 += logd * ws4.z; v3 += logd * ws4.w;
                } else {
                    float ind[5];
#pragma unroll
                    for (int k = 0; k < 5; ++k) {
                        int p = 2 * t + k - 2;
                        ind[k] = (p >= 0 && p < Nb) ? logd : 0.f;
                    }
                    float sv[4] = {0.f, 0.f, 0.f, 0.f};
#pragma unroll
                    for (int j = 0; j < 4; ++j)
#pragma unroll
                        for (int k = 0; k < 5; ++k) sv[j] += ind[k] * wd1[(ocg0 + j) * 5 + k];
                    v0 += sv[0]; v1 += sv[1]; v2 += sv[2]; v3 += sv[3];
                }
            }
            v0 += bias.x; v1 += bias.y; v2 += bias.z; v3 += bias.w;
            if (!is_r) {
                float4 o; o.x = v0; o.y = v1; o.z = v2; o.w = v3;
                *(float4*)(Lout + ((size_t)(b * T_out) + t) * 256 + ocg0) = o;
            } else {
                bool live = (t < Nn);
                float r0v = live ? fmaxf(v0, 0.f) : 0.f;
                float r1v = live ? fmaxf(v1, 0.f) : 0.f;
                float r2v = live ? fmaxf(v2, 0.f) : 0.f;
                float r3v = live ? fmaxf(v3, 0.f) : 0.f;
                int ocr = ocg0 - 256;
                char* rrow = Rout + ((size_t)(b * T_out) + t) * 1024;
                ushort4 H, L2;
                H.x = bf_hi_bits(r0v); L2.x = bf_hi_bits(r0v - bf_hi_f(r0v));
                H.y = bf_hi_bits(r1v); L2.y = bf_hi_bits(r1v - bf_hi_f(r1v));
                H.z = bf_hi_bits(r2v); L2.z = bf_hi_bits(r2v - bf_hi_f(r2v));
                H.w = bf_hi_bits(r3v); L2.w = bf_hi_bits(r3v - bf_hi_f(r3v));
                *(ushort4*)(rrow + ocr * 2) = H;
                *(ushort4*)(rrow + 512 + ocr * 2) = L2;
            }
        }
    }
}

// ------------- conv2: h = relu(l + conv(r, w2, 1) + b2), in-place ----------
// Block 256 oc x 64 t; K staged in 2 c-halves (68 rows x 512B = 34.8 KB LDS).
__global__ __launch_bounds__(256, 4)
void conv2_kernel(const char* __restrict__ Rin,
                  const unsigned short* __restrict__ Whi, const unsigned short* __restrict__ Wlo,
                  const float* __restrict__ b2, const int* __restrict__ N0,
                  const int* __restrict__ rankfd, float* __restrict__ LH,
                  float* __restrict__ out, int T, int depth) {
    __shared__ __align__(16) char smem[68 * 512];
    const int tid = threadIdx.x;
    const int w = tid >> 6, l = tid & 63;
    const int b = blockIdx.z;
    const int t0 = blockIdx.x * 64;
    const int n0 = N0[b];
    const int Nn = (n0 + (1 << (depth + 1)) - 1) >> (depth + 1);

    if (t0 >= Nn) {   // h rows are zero here; next conv1 reads them
        int row = t0 + (tid >> 2);
        if (row < T) {
            char* hp = (char*)LH + ((size_t)(b * T) + row) * 1024 + (tid & 3) * 256;
            uint4 z = make_uint4(0, 0, 0, 0);
#pragma unroll
            for (int qq = 0; qq < 16; ++qq) *(uint4*)(hp + qq * 16) = z;
        }
        return;
    }

    f32x4 acc[4][4];
#pragma unroll
    for (int i = 0; i < 4; ++i)
#pragma unroll
        for (int j = 0; j < 4; ++j) acc[i][j] = f32x4{0.f, 0.f, 0.f, 0.f};

    const int sg_g16 = l & 15;
    const int sg_seg = (l >> 4) & 1;
    const int sg_rb0 = w * 2 + (l >> 5);

#pragma unroll 1
    for (int hf = 0; hf < 2; ++hf) {
        if (hf) __syncthreads();
        for (int rb = sg_rb0; rb < 68; rb += 8) {
            int p = t0 - 2 + rb;
            uint4 v = make_uint4(0, 0, 0, 0);
            if (p >= 0 && p < T)
                v = *(const uint4*)(Rin + ((size_t)(b * T) + p) * 1024 + sg_seg * 512 + hf * 256 + sg_g16 * 16);
            int phys = (sg_g16 ^ (rb & 7)) | (sg_seg << 4);
            *(uint4*)(smem + rb * 512 + phys * 16) = v;
        }
        __syncthreads();
#pragma unroll
        for (int k = 0; k < 5; ++k) {
#pragma unroll
            for (int cc = 0; cc < 4; ++cc) {
                const int chunk = k * 8 + hf * 4 + cc;
                bf16x8 Bh[4], Bl[4];
#pragma unroll
                for (int tt = 0; tt < 4; ++tt) {
                    int s = tt * 16 + (l & 15) + k;
                    int gq = cc * 4 + (l >> 4);
                    int ph = gq ^ (s & 7);
                    Bh[tt] = as_bf16x8(*(const uint4*)(smem + s * 512 + ph * 16));
                    Bl[tt] = as_bf16x8(*(const uint4*)(smem + s * 512 + (ph | 16) * 16));
                }
#pragma unroll
                for (int ot = 0; ot < 4; ++ot) {
                    size_t aoff = ((size_t)(chunk * 16 + w * 4 + ot)) * 512 + l * 8;
                    bf16x8 Ah = as_bf16x8(*(const uint4*)(Whi + aoff));
                    bf16x8 Al = as_bf16x8(*(const uint4*)(Wlo + aoff));
#pragma unroll
                    for (int tt = 0; tt < 4; ++tt) {
                        acc[ot][tt] = MFMA(Ah, Bh[tt], acc[ot][tt]);
                        acc[ot][tt] = MFMA(Ah, Bl[tt], acc[ot][tt]);
                        acc[ot][tt] = MFMA(Al, Bh[tt], acc[ot][tt]);
                    }
                }
            }
        }
    }

    // ---- epilogue: l + acc + bias, relu, mask, capture; barrier; in-place h ----
    const int q = l >> 4;
    const int n = l & 15;
    const int rk = rankfd[b];
    const int fd = rankfd[64 + b];
#pragma unroll
    for (int ot = 0; ot < 4; ++ot) {
        const int ocg0 = (w * 4 + ot) * 16 + q * 4;
        float4 bias = *(const float4*)(b2 + ocg0);
#pragma unroll
        for (int tt = 0; tt < 4; ++tt) {
            int t = t0 + tt * 16 + n;
            float v0 = 0.f, v1 = 0.f, v2 = 0.f, v3 = 0.f;
            if (t < T && t < Nn) {
                float4 l4 = *(const float4*)(LH + ((size_t)(b * T) + t) * 256 + ocg0);
                v0 = fmaxf(acc[ot][tt].x + l4.x + bias.x, 0.f);
                v1 = fmaxf(acc[ot][tt].y + l4.y + bias.y, 0.f);
                v2 = fmaxf(acc[ot][tt].z + l4.z + bias.z, 0.f);
                v3 = fmaxf(acc[ot][tt].w + l4.w + bias.w, 0.f);
                if (t == 0 && depth == fd) {
                    float4 o; o.x = v0; o.y = v1; o.z = v2; o.w = v3;
                    *(float4*)(out + rk * 256 + ocg0) = o;
                }
            }
            acc[ot][tt] = f32x4{v0, v1, v2, v3};   // reuse acc as value buffer
        }
    }
    __syncthreads();   // all l-reads complete before in-place overwrite
#pragma unroll
    for (int ot = 0; ot < 4; ++ot) {
        const int ocg0 = (w * 4 + ot) * 16 + q * 4;
#pragma unroll
        for (int tt = 0; tt < 4; ++tt) {
            int t = t0 + tt * 16 + n;
            if (t >= T) continue;
            char* hrow = (char*)LH + ((size_t)(b * T) + t) * 1024;
            float v0 = acc[ot][tt].x, v1 = acc[ot][tt].y, v2 = acc[ot][tt].z, v3 = acc[ot][tt].w;
            ushort4 H, L2;
            H.x = bf_hi_bits(v0); L2.x = bf_hi_bits(v0 - bf_hi_f(v0));
            H.y = bf_hi_bits(v1); L2.y = bf_hi_bits(v1 - bf_hi_f(v1));
            H.z = bf_hi_bits(v2); L2.z = bf_hi_bits(v2 - bf_hi_f(v2));
            H.w = bf_hi_bits(v3); L2.w = bf_hi_bits(v3 - bf_hi_f(v3));
            *(ushort4*)(hrow + ocg0 * 2) = H;
            *(ushort4*)(hrow + 512 + ocg0 * 2) = L2;
        }
    }
}

// --------------------------------- launch ----------------------------------
extern "C" void kernel_launch(void* const* d_in, const int* in_sizes, int n_in,
                              void* d_out, int out_size, void* d_ws, size_t ws_size,
                              hipStream_t stream) {
    const float* h  = (const float*)d_in[0];
    const int*   N0 = (const int*)d_in[1];
    const float* w1 = (const float*)d_in[2];
    const float* b1 = (const float*)d_in[3];
    const float* w2 = (const float*)d_in[4];
    const float* b2 = (const float*)d_in[5];
    float* out = (float*)d_out;

    char* ws = (char*)d_ws;
    size_t off = 0;
    auto alloc = [&](size_t bytes) -> void* {
        void* p = ws + off;
        off = (off + bytes + 255) & ~(size_t)255;
        return p;
    };
    int* rankfd            = (int*)alloc(512);
    float* wd1             = (float*)alloc(512 * 5 * 4);
    float* wsum1           = (float*)alloc(512 * 4);
    unsigned short* Whi1   = (unsigned short*)alloc((size_t)655360 * 2);
    unsigned short* Wlo1   = (unsigned short*)alloc((size_t)655360 * 2);
    unsigned short* Whi2   = (unsigned short*)alloc((size_t)327680 * 2);
    unsigned short* Wlo2   = (unsigned short*)alloc((size_t)327680 * 2);
    float* P1              = (float*)alloc((size_t)64 * 2048 * 1024);   // even-depth h rows
    char*  H4096           = (char*)alloc((size_t)64 * 4096 * 1024);   // depth-0 input
    float* P0              = (float*)H4096;   // alias: H4096 dead after d0 conv1
    char*  R               = (char*)alloc((size_t)64 * 2048 * 1024);
    (void)ws_size;

    setup_kernel<<<1, 64, 0, stream>>>(N0, rankfd);
    {
        int total = 655360 + 327680 + 512;
        prepack_kernel<<<(total + 255) / 256, 256, 0, stream>>>(w1, w2, Whi1, Wlo1, Whi2, Wlo2, wd1, wsum1);
    }
    transpose_kernel<<<dim3(32, 4, 64), 256, 0, stream>>>(h, N0, H4096);

    int T_in = 4096;
    for (int d = 0; d < 12; ++d) {
        int To = T_in >> 1;
        float* LH = (d & 1) ? P0 : P1;
        const char* Hin = (d == 0) ? (const char*)H4096 : (const char*)((d & 1) ? P1 : P0);
        float logd = log1pf((float)d);
        dim3 g1((To + 63) / 64, 2, 64);
        conv1_kernel<<<g1, 256, 0, stream>>>(Hin, Whi1, Wlo1, b1, wd1, wsum1, N0,
                                             LH, R, T_in, To, d, logd);
        dim3 g2((To + 63) / 64, 1, 64);
        conv2_kernel<<<g2, 256, 0, stream>>>(R, Whi2, Wlo2, b2, N0, rankfd, LH, out, To, d);
        T_in = To;
    }
}